// Round 13
// baseline (42.784 us; speedup 1.0000x reference)
//
#include <hip/hip_runtime.h>
#include <math.h>

// NetVLAD fused pipeline, MFMA bf16. R13: REST-SIDE DECOMPOSITION PROBE —
// B, C, D each launched TWICE (idempotent; output identical) to measure
// t_B+t_C+t_D = dur(R13) - dur(R12). A/B/C/D code byte-identical to R12
// (best known, 35.54us).
// x[32][128][4096], conv_w[64][128], conv_b[64], centers[64][128],
// mlp_w[256][8192], mlp_b[256], out[32][256].

#define N_IMG 32
#define C_DIM 128
#define P_PIX 4096
#define K_CL  64
#define OUT_D 256

#define CHUNKS 8               // chunks per image (512 px each)
#define NSUB 4                 // 128-px subchunks per chunk
#define PART_ROW 132
#define PART_BLK (K_CL * PART_ROW)

typedef __attribute__((ext_vector_type(8))) short bf16x8;
typedef __attribute__((ext_vector_type(4))) short bf16x4;
typedef __attribute__((ext_vector_type(4))) float f32x4;
typedef __attribute__((ext_vector_type(2))) unsigned u32x2;
typedef __attribute__((ext_vector_type(4))) unsigned u32x4;

// hardware packed f32->bf16 (RTNE), lo = a, hi = b
__device__ __forceinline__ unsigned cvtpk(float a, float b) {
    unsigned r;
    asm("v_cvt_pk_bf16_f32 %0, %1, %2" : "=v"(r) : "v"(a), "v"(b));
    return r;
}
__device__ __forceinline__ unsigned short bf1(float a) {
    union { float f; unsigned u; } x; x.f = a;
    return (unsigned short)((x.u + 0x7FFFu + ((x.u >> 16) & 1u)) >> 16);
}

__device__ __forceinline__ f32x4 mfma16(bf16x8 a, bf16x8 b, f32x4 c) {
    return __builtin_amdgcn_mfma_f32_16x16x32_bf16(a, b, c, 0, 0, 0);
}

__device__ __forceinline__ u32x2 tr16(unsigned addr) {
    u32x2 d;
    asm volatile("ds_read_b64_tr_b16 %0, %1" : "=v"(d) : "v"(addr));
    return d;
}
__device__ __forceinline__ u32x2 tr16_o1024(unsigned addr) {
    u32x2 d;
    asm volatile("ds_read_b64_tr_b16 %0, %1 offset:1024" : "=v"(d) : "v"(addr));
    return d;
}

// raw barrier: drain LDS only, leave global prefetch loads in flight
__device__ __forceinline__ void bar_lgkm() {
    __builtin_amdgcn_sched_barrier(0);
    asm volatile("s_waitcnt lgkmcnt(0)" ::: "memory");
    __builtin_amdgcn_s_barrier();
    __builtin_amdgcn_sched_barrier(0);
}

// DPP 16-lane-row reductions (VALU latency, no LDS round-trip)
template<int CTRL>
__device__ __forceinline__ float dppmv(float v) {
    union { float f; int i; } u; u.f = v;
    u.i = __builtin_amdgcn_update_dpp(u.i, u.i, CTRL, 0xF, 0xF, false);
    return u.f;
}
__device__ __forceinline__ float rowmax16(float v) {
    v = fmaxf(v, dppmv<0xB1>(v));
    v = fmaxf(v, dppmv<0x4E>(v));
    v = fmaxf(v, dppmv<0x141>(v));
    v = fmaxf(v, dppmv<0x140>(v));
    return v;
}
__device__ __forceinline__ float rowsum16(float v) {
    v += dppmv<0xB1>(v);
    v += dppmv<0x4E>(v);
    v += dppmv<0x141>(v);
    v += dppmv<0x140>(v);
    return v;
}

// ---------------------------------------------------------------------------
// Kernel A (== R12): fused conv-logits + softmax + VLAD partials on MFMA.
// grid = 256 (n = bid>>3, 512-px chunk = bid&7), block = 512 (8 waves).
// ---------------------------------------------------------------------------
__global__ __launch_bounds__(512, 2)
void k_vlad_mfma(const float* __restrict__ x, const float* __restrict__ conv_w,
                 const float* __restrict__ conv_b, float* __restrict__ part)
{
    __shared__ short xc_s[16384];   // x subtiled [c>>2][p>>4][c&3][p&15], 32 KB
    __shared__ short a_s[8192];     // a[k][p] bf16, byte ^ ((k&7)<<4), 16 KB
    __shared__ short w_s[8192];     // W[k][c] bf16 (LOG2E-scaled), swizzled, 16 KB
    __shared__ float asred[512];

    const int t   = threadIdx.x;
    const int w   = t >> 6;         // wave 0..7
    const int l   = t & 63;
    const int l15 = l & 15;
    const int lg  = l >> 4;
    const int n   = blockIdx.x >> 3;
    const int ch  = blockIdx.x & 7;
    const int pb0 = ch * 512;

    const unsigned xc_base = (unsigned)(unsigned long long)(void*)xc_s;
    const float LOG2E = 1.44269504f;

    // ---- prologue: issue subchunk-0 x loads (wave's 16 c-rows) ----
    const float* xr0 = x + ((long)n * C_DIM + 16 * w + l15) * P_PIX;
    float4 raw[8];
#pragma unroll
    for (int ks = 0; ks < 4; ++ks) {
        const float* p = xr0 + pb0 + ks * 32 + lg * 8;
        raw[ks * 2 + 0] = *(const float4*)(p);
        raw[ks * 2 + 1] = *(const float4*)(p + 4);
    }

    // ---- stage W -> LDS (bf16, LOG2E-prescaled, XOR-swizzled), 512 thr ----
    {
        const int k = t >> 3, sub = t & 7;
        const float* wr = conv_w + k * C_DIM + sub * 16;
#pragma unroll
        for (int j = 0; j < 2; ++j) {
            float4 a = *(const float4*)(wr + j * 8);
            float4 b = *(const float4*)(wr + j * 8 + 4);
            union { u32x4 u; bf16x8 v; } cv;
            cv.u.x = cvtpk(a.x * LOG2E, a.y * LOG2E);
            cv.u.y = cvtpk(a.z * LOG2E, a.w * LOG2E);
            cv.u.z = cvtpk(b.x * LOG2E, b.y * LOG2E);
            cv.u.w = cvtpk(b.z * LOG2E, b.w * LOG2E);
            const int g = sub * 2 + j;
            const unsigned off = (unsigned)(k * 256 + ((g * 16) ^ ((k & 7) << 4)));
            *(bf16x8*)((char*)w_s + off) = cv.v;
        }
    }
    float bias[4];
#pragma unroll
    for (int nt = 0; nt < 4; ++nt) bias[nt] = conv_b[nt * 16 + l15] * LOG2E;

    bar_lgkm();   // W staged (prologue global loads stay in flight)

    // ---- hoist W-frags to registers (read LDS once per block) ----
    bf16x8 wf[4][4];
#pragma unroll
    for (int nt = 0; nt < 4; ++nt)
#pragma unroll
        for (int ks = 0; ks < 4; ++ks) {
            const unsigned wb = (unsigned)((nt * 16 + l15) * 256
                + ((ks * 64 + lg * 16) ^ ((l15 & 7) << 4)));
            wf[nt][ks] = *(const bf16x8*)((char*)w_s + wb);
        }

    f32x4 acc2[4];                  // vlad acc: [mt over k], c-slice = 16w+l15
#pragma unroll
    for (int mt = 0; mt < 4; ++mt) acc2[mt] = (f32x4){0.f, 0.f, 0.f, 0.f};
    float asum[4] = {0.f, 0.f, 0.f, 0.f};
    bf16x8 oct[4];                  // x bf16 octets: GEMM2 B-frags (own c-slice)

#pragma unroll
    for (int s = 0; s < NSUB; ++s) {
        // ---- convert raw -> bf16 octets ----
#pragma unroll
        for (int ks = 0; ks < 4; ++ks) {
            const float4 A = raw[ks * 2];
            const float4 B = raw[ks * 2 + 1];
            union { u32x4 u; bf16x8 v; } cv;
            cv.u.x = cvtpk(A.x, A.y); cv.u.y = cvtpk(A.z, A.w);
            cv.u.z = cvtpk(B.x, B.y); cv.u.w = cvtpk(B.z, B.w);
            oct[ks] = cv.v;
        }
        // ---- stage into subtiled xc (own 16 c-rows) ----
#pragma unroll
        for (int ks = 0; ks < 4; ++ks) {
            const int c  = 16 * w + l15;
            const int pl = ks * 32 + lg * 8;
            const unsigned off = (unsigned)((c >> 2) * 1024 + (pl >> 4) * 128
                                            + (c & 3) * 32 + (pl & 15) * 2);
            *(bf16x8*)((char*)xc_s + off) = oct[ks];
        }
        // ---- prefetch next subchunk (in flight across barriers) ----
        if (s + 1 < NSUB) {
#pragma unroll
            for (int ks = 0; ks < 4; ++ks) {
                const float* p = xr0 + pb0 + (s + 1) * 128 + ks * 32 + lg * 8;
                raw[ks * 2 + 0] = *(const float4*)(p);
                raw[ks * 2 + 1] = *(const float4*)(p + 4);
            }
        }
        bar_lgkm();   // B1: xc staged

        // ---- GEMM1: logits^T for own p-tile (16p x 64k), batched tr ----
        u32x2 trr[4][2];
#pragma unroll
        for (int ks = 0; ks < 4; ++ks) {
            const unsigned ab = xc_base
                + (unsigned)((ks * 8 + lg * 2) * 1024 + l15 * 2 + w * 128);
            trr[ks][0] = tr16(ab);
            trr[ks][1] = tr16_o1024(ab);
        }
        asm volatile("s_waitcnt lgkmcnt(0)" ::: "memory");
        __builtin_amdgcn_sched_barrier(0);

        f32x4 acc1[4];
#pragma unroll
        for (int nt = 0; nt < 4; ++nt) acc1[nt] = (f32x4){0.f, 0.f, 0.f, 0.f};
#pragma unroll
        for (int ks = 0; ks < 4; ++ks) {
            union { u32x4 u; bf16x8 v; } a0;
            a0.u = (u32x4){trr[ks][0].x, trr[ks][0].y, trr[ks][1].x, trr[ks][1].y};
#pragma unroll
            for (int nt = 0; nt < 4; ++nt)
                acc1[nt] = mfma16(a0.v, wf[nt][ks], acc1[nt]);
        }

        // ---- softmax over k=64 (4 r-iters; DPP row reduce, exp2 domain) ----
#pragma unroll
        for (int r = 0; r < 4; ++r) {
            float v0 = acc1[0][r] + bias[0];
            float v1 = acc1[1][r] + bias[1];
            float v2 = acc1[2][r] + bias[2];
            float v3 = acc1[3][r] + bias[3];
            float m = fmaxf(fmaxf(v0, v1), fmaxf(v2, v3));
            m = rowmax16(m);
            v0 = exp2f(v0 - m); v1 = exp2f(v1 - m);
            v2 = exp2f(v2 - m); v3 = exp2f(v3 - m);
            float sm = (v0 + v1) + (v2 + v3);
            sm = rowsum16(sm);
            const float inv = __builtin_amdgcn_rcpf(sm);
            v0 *= inv; v1 *= inv; v2 *= inv; v3 *= inv;
            asum[0] += v0; asum[1] += v1; asum[2] += v2; asum[3] += v3;
            acc1[0][r] = v0; acc1[1][r] = v1; acc1[2][r] = v2; acc1[3][r] = v3;
        }

        // ---- write a -> a_s (swizzled); own p-tile ----
        {
            const int pbyte = w * 32 + lg * 8;
#pragma unroll
            for (int nt = 0; nt < 4; ++nt) {
                const int k = nt * 16 + l15;
                union { u32x2 u; bf16x4 v; } pk4;
                pk4.u.x = cvtpk(acc1[nt][0], acc1[nt][1]);
                pk4.u.y = cvtpk(acc1[nt][2], acc1[nt][3]);
                const unsigned off =
                    (unsigned)(k * 256 + (pbyte ^ ((k & 7) << 4)));
                *(bf16x4*)((char*)a_s + off) = pk4.v;
            }
        }
        bar_lgkm();   // B2: a ready

        // ---- GEMM2: vlad[k][own c-slice] += a[k][p] @ x^T[p][c] ----
#pragma unroll
        for (int ks = 0; ks < 4; ++ks) {
            bf16x8 af[4];
#pragma unroll
            for (int mt = 0; mt < 4; ++mt) {
                const int k = mt * 16 + l15;
                const unsigned off = (unsigned)(k * 256
                    + ((ks * 64 + lg * 16) ^ ((k & 7) << 4)));
                af[mt] = *(const bf16x8*)((char*)a_s + off);
            }
#pragma unroll
            for (int mt = 0; mt < 4; ++mt)
                acc2[mt] = mfma16(af[mt], oct[ks], acc2[mt]);
        }
    }

    // ---- write partials: part[bid][k][c], asum at c=128 ----
    const long pbase = (long)blockIdx.x * PART_BLK;
    {
        const int c = 16 * w + l15;
#pragma unroll
        for (int mt = 0; mt < 4; ++mt)
#pragma unroll
            for (int r = 0; r < 4; ++r) {
                const int k = mt * 16 + lg * 4 + r;
                part[pbase + (long)k * PART_ROW + c] = acc2[mt][r];
            }
    }
#pragma unroll
    for (int nt = 0; nt < 4; ++nt) {
        float a = asum[nt];
        a += __shfl_xor(a, 16);
        a += __shfl_xor(a, 32);
        if (lg == 0) asred[w * 64 + nt * 16 + l15] = a;
    }
    __syncthreads();
    if (t < 64) {
        float a = 0.f;
#pragma unroll
        for (int j = 0; j < 8; ++j) a += asred[j * 64 + t];
        part[pbase + (long)t * PART_ROW + 128] = a;
    }
}

// ---------------------------------------------------------------------------
// Kernel B (== R12): reduce partials, subtract asum*centers, intra-normalize.
// ---------------------------------------------------------------------------
__global__ __launch_bounds__(128)
void k_reduce_norm(const float* __restrict__ part, const float* __restrict__ centers,
                   unsigned short* __restrict__ vn16, float* __restrict__ rsq)
{
    const int b = blockIdx.x;
    const int n = b >> 6, k = b & 63;
    const int c = threadIdx.x;
    float acc = 0.f, as = 0.f;
#pragma unroll
    for (int ch = 0; ch < CHUNKS; ++ch) {
        const float* p = part + ((long)(n * CHUNKS + ch) * PART_BLK + k * PART_ROW);
        acc += p[c];
        as  += p[128];
    }
    const float v = fmaf(-as, centers[k * C_DIM + c], acc);
    float sq = v * v;
#pragma unroll
    for (int m = 1; m < 64; m <<= 1) sq += __shfl_xor(sq, m);
    __shared__ float red[2];
    if ((c & 63) == 0) red[c >> 6] = sq;
    __syncthreads();
    const float total = red[0] + red[1];
    const float s = 1.0f / fmaxf(sqrtf(total), 1e-12f);
    vn16[(long)n * 8192 + k * C_DIM + c] = bf1(v * s);
    if (c == 0) rsq[n * K_CL + k] = total * s * s;
}

// ---------------------------------------------------------------------------
// Kernel C (== R12): MLP GEMM, LDS-staged coalesced. grid = 256.
// ---------------------------------------------------------------------------
__global__ __launch_bounds__(256)
void k_mlp_mfma(const unsigned short* __restrict__ vn16,
                const float* __restrict__ mlp_w, float* __restrict__ part2)
{
    __shared__ short wt[8192];   // W  tile bf16 [32 o][256 j], swizzled, 16 KB
    __shared__ short vt[8192];   // vn tile bf16 [32 n][256 j], swizzled, 16 KB

    const int t  = threadIdx.x;
    const int og = blockIdx.x & 7;
    const int jc = blockIdx.x >> 3;
    const int j0 = jc * 256;

    {
        const int r = t >> 3, sub = t & 7;
        const float* wp = mlp_w + (long)(og * 32 + r) * 8192 + j0;
#pragma unroll
        for (int i = 0; i < 8; ++i) {
            const int jl = i * 32 + sub * 4;
            float4 a = *(const float4*)(wp + jl);
            union { u32x2 u; bf16x4 v; } cv;
            cv.u.x = cvtpk(a.x, a.y);
            cv.u.y = cvtpk(a.z, a.w);
            const unsigned off = (unsigned)(r * 512 + ((jl * 2) ^ ((r & 7) << 4)));
            *(bf16x4*)((char*)wt + off) = cv.v;
        }
    }
    {
        const int r = t >> 3, sub = t & 7;
        const unsigned short* vp = vn16 + (long)r * 8192 + j0;
#pragma unroll
        for (int i = 0; i < 4; ++i) {
            const int jl = i * 64 + sub * 8;
            bf16x8 v = *(const bf16x8*)(vp + jl);
            const unsigned off = (unsigned)(r * 512 + ((jl * 2) ^ ((r & 7) << 4)));
            *(bf16x8*)((char*)vt + off) = v;
        }
    }
    __syncthreads();

    const int w = t >> 6, l = t & 63, l15 = l & 15, lg = l >> 4;
    const int mt = w >> 1, ot = w & 1;
    f32x4 acc = (f32x4){0.f, 0.f, 0.f, 0.f};
#pragma unroll
    for (int kk = 0; kk < 8; ++kk) {
        const int rowa = mt * 16 + l15;
        const int rowb = ot * 16 + l15;
        const int jb = (kk * 32 + lg * 8) * 2;
        bf16x8 af = *(const bf16x8*)((char*)vt
                        + (unsigned)(rowa * 512 + (jb ^ ((rowa & 7) << 4))));
        bf16x8 bf = *(const bf16x8*)((char*)wt
                        + (unsigned)(rowb * 512 + (jb ^ ((rowb & 7) << 4))));
        acc = mfma16(af, bf, acc);
    }
#pragma unroll
    for (int r = 0; r < 4; ++r) {
        const int nn = mt * 16 + lg * 4 + r;
        const int oo = og * 32 + ot * 16 + l15;
        part2[(long)nn * 8192 + jc * 256 + oo] = acc[r];
    }
}

// ---------------------------------------------------------------------------
// Kernel D (== R12): reduce jc-slices, global-norm, bias, final L2 norm.
// ---------------------------------------------------------------------------
__global__ __launch_bounds__(1024)
void k_finalize(const float* __restrict__ part2, const float* __restrict__ mlp_b,
                const float* __restrict__ rsq, float* __restrict__ out)
{
    __shared__ float psum[4][256];
    __shared__ float red[4];
    const int n = blockIdx.x;
    const int t = threadIdx.x;
    const int o = t & 255, q = t >> 8;

    float acc = 0.f;
#pragma unroll
    for (int j = 0; j < 8; ++j)
        acc += part2[(long)n * 8192 + (q * 8 + j) * 256 + o];
    psum[q][o] = acc;
    __syncthreads();

    float y = 0.f;
    if (q == 0) {
        float g = 0.f;
#pragma unroll
        for (int i = 0; i < 16; ++i) {
            const float4 r = *(const float4*)&rsq[n * K_CL + i * 4];
            g += r.x + r.y + r.z + r.w;
        }
        const float s = 1.0f / fmaxf(sqrtf(g), 1e-12f);
        const float tot = psum[0][o] + psum[1][o] + psum[2][o] + psum[3][o];
        y = fmaf(tot * s, 1.0f, mlp_b[o]);
        float sq = y * y;
#pragma unroll
        for (int m = 1; m < 64; m <<= 1) sq += __shfl_xor(sq, m);
        if ((o & 63) == 0) red[o >> 6] = sq;
    }
    __syncthreads();
    if (q == 0) {
        const float tot2 = red[0] + red[1] + red[2] + red[3];
        out[n * OUT_D + o] = y / fmaxf(sqrtf(tot2), 1e-12f);
    }
}

// ---------------------------------------------------------------------------
extern "C" void kernel_launch(void* const* d_in, const int* in_sizes, int n_in,
                              void* d_out, int out_size, void* d_ws, size_t ws_size,
                              hipStream_t stream)
{
    const float* x       = (const float*)d_in[0];
    const float* centers = (const float*)d_in[1];
    const float* conv_w  = (const float*)d_in[2];
    const float* conv_b  = (const float*)d_in[3];
    const float* mlp_w   = (const float*)d_in[4];
    const float* mlp_b   = (const float*)d_in[5];

    float* ws = (float*)d_ws;
    float* part = ws;                                   // 256*8448 f
    unsigned short* vn16 = (unsigned short*)(part + 256 * PART_BLK);  // 262,144 u16
    float* rsq   = (float*)(vn16 + 32 * 8192);          // 2,048 f
    float* part2 = rsq + 2048;                          // 32*8192 f

    // PROBE: B, C, D each launched twice (idempotent). t_BCD = R13 - R12.
    k_vlad_mfma<<<dim3(256), dim3(512), 0, stream>>>(x, conv_w, conv_b, part);
    k_reduce_norm<<<dim3(2048), dim3(128), 0, stream>>>(part, centers, vn16, rsq);
    k_reduce_norm<<<dim3(2048), dim3(128), 0, stream>>>(part, centers, vn16, rsq);
    k_mlp_mfma<<<dim3(256), dim3(256), 0, stream>>>(vn16, mlp_w, part2);
    k_mlp_mfma<<<dim3(256), dim3(256), 0, stream>>>(vn16, mlp_w, part2);
    k_finalize<<<dim3(32), dim3(1024), 0, stream>>>(part2, mlp_b, rsq, (float*)d_out);
    k_finalize<<<dim3(32), dim3(1024), 0, stream>>>(part2, mlp_b, rsq, (float*)d_out);
}

// Round 14
// 35.327 us; speedup vs baseline: 1.2111x; 1.2111x over previous
//
#include <hip/hip_runtime.h>
#include <math.h>

// NetVLAD fused pipeline, MFMA bf16. R14: kernel A schedule v2 — xc staging
// and next-subchunk conversion moved into the GEMM2 shadow (after B2), so
// stage writes + prefetch wait overlap MFMAs instead of sitting on the
// critical path before B1. B/C/D identical to R12/R10 (best known).
// x[32][128][4096], conv_w[64][128], conv_b[64], centers[64][128],
// mlp_w[256][8192], mlp_b[256], out[32][256].

#define N_IMG 32
#define C_DIM 128
#define P_PIX 4096
#define K_CL  64
#define OUT_D 256

#define CHUNKS 8               // chunks per image (512 px each)
#define NSUB 4                 // 128-px subchunks per chunk
#define PART_ROW 132
#define PART_BLK (K_CL * PART_ROW)

typedef __attribute__((ext_vector_type(8))) short bf16x8;
typedef __attribute__((ext_vector_type(4))) short bf16x4;
typedef __attribute__((ext_vector_type(4))) float f32x4;
typedef __attribute__((ext_vector_type(2))) unsigned u32x2;
typedef __attribute__((ext_vector_type(4))) unsigned u32x4;

// hardware packed f32->bf16 (RTNE), lo = a, hi = b
__device__ __forceinline__ unsigned cvtpk(float a, float b) {
    unsigned r;
    asm("v_cvt_pk_bf16_f32 %0, %1, %2" : "=v"(r) : "v"(a), "v"(b));
    return r;
}
__device__ __forceinline__ unsigned short bf1(float a) {
    union { float f; unsigned u; } x; x.f = a;
    return (unsigned short)((x.u + 0x7FFFu + ((x.u >> 16) & 1u)) >> 16);
}

__device__ __forceinline__ f32x4 mfma16(bf16x8 a, bf16x8 b, f32x4 c) {
    return __builtin_amdgcn_mfma_f32_16x16x32_bf16(a, b, c, 0, 0, 0);
}

__device__ __forceinline__ u32x2 tr16(unsigned addr) {
    u32x2 d;
    asm volatile("ds_read_b64_tr_b16 %0, %1" : "=v"(d) : "v"(addr));
    return d;
}
__device__ __forceinline__ u32x2 tr16_o1024(unsigned addr) {
    u32x2 d;
    asm volatile("ds_read_b64_tr_b16 %0, %1 offset:1024" : "=v"(d) : "v"(addr));
    return d;
}

// raw barrier: drain LDS only, leave global prefetch loads in flight
__device__ __forceinline__ void bar_lgkm() {
    __builtin_amdgcn_sched_barrier(0);
    asm volatile("s_waitcnt lgkmcnt(0)" ::: "memory");
    __builtin_amdgcn_s_barrier();
    __builtin_amdgcn_sched_barrier(0);
}

// DPP 16-lane-row reductions (VALU latency, no LDS round-trip)
template<int CTRL>
__device__ __forceinline__ float dppmv(float v) {
    union { float f; int i; } u; u.f = v;
    u.i = __builtin_amdgcn_update_dpp(u.i, u.i, CTRL, 0xF, 0xF, false);
    return u.f;
}
__device__ __forceinline__ float rowmax16(float v) {
    v = fmaxf(v, dppmv<0xB1>(v));
    v = fmaxf(v, dppmv<0x4E>(v));
    v = fmaxf(v, dppmv<0x141>(v));
    v = fmaxf(v, dppmv<0x140>(v));
    return v;
}
__device__ __forceinline__ float rowsum16(float v) {
    v += dppmv<0xB1>(v);
    v += dppmv<0x4E>(v);
    v += dppmv<0x141>(v);
    v += dppmv<0x140>(v);
    return v;
}

// ---------------------------------------------------------------------------
// Kernel A: fused conv-logits + softmax + VLAD partials on MFMA.
// grid = 256 (n = bid>>3, 512-px chunk = bid&7), block = 512 (8 waves,
// 2 waves/SIMD). Schedule v2: per subchunk
//   B1 -> GEMM1(tr) -> softmax -> a_s write -> B2 ->
//   GEMM2(s) || convert+stage xc(s+1) || prefetch raw(s+2)
// so staging sits in the MFMA shadow, not before B1.
// ---------------------------------------------------------------------------
__global__ __launch_bounds__(512, 2)
void k_vlad_mfma(const float* __restrict__ x, const float* __restrict__ conv_w,
                 const float* __restrict__ conv_b, float* __restrict__ part)
{
    __shared__ short xc_s[16384];   // x subtiled [c>>2][p>>4][c&3][p&15], 32 KB
    __shared__ short a_s[8192];     // a[k][p] bf16, byte ^ ((k&7)<<4), 16 KB
    __shared__ short w_s[8192];     // W[k][c] bf16 (LOG2E-scaled), swizzled, 16 KB
    __shared__ float asred[512];

    const int t   = threadIdx.x;
    const int w   = t >> 6;         // wave 0..7
    const int l   = t & 63;
    const int l15 = l & 15;
    const int lg  = l >> 4;
    const int n   = blockIdx.x >> 3;
    const int ch  = blockIdx.x & 7;
    const int pb0 = ch * 512;

    const unsigned xc_base = (unsigned)(unsigned long long)(void*)xc_s;
    const float LOG2E = 1.44269504f;

    // ---- prologue: issue subchunk-0 x loads (wave's 16 c-rows) ----
    const float* xr0 = x + ((long)n * C_DIM + 16 * w + l15) * P_PIX;
    float4 raw[8];
#pragma unroll
    for (int ks = 0; ks < 4; ++ks) {
        const float* p = xr0 + pb0 + ks * 32 + lg * 8;
        raw[ks * 2 + 0] = *(const float4*)(p);
        raw[ks * 2 + 1] = *(const float4*)(p + 4);
    }

    // ---- stage W -> LDS (bf16, LOG2E-prescaled, XOR-swizzled), 512 thr ----
    {
        const int k = t >> 3, sub = t & 7;
        const float* wr = conv_w + k * C_DIM + sub * 16;
#pragma unroll
        for (int j = 0; j < 2; ++j) {
            float4 a = *(const float4*)(wr + j * 8);
            float4 b = *(const float4*)(wr + j * 8 + 4);
            union { u32x4 u; bf16x8 v; } cv;
            cv.u.x = cvtpk(a.x * LOG2E, a.y * LOG2E);
            cv.u.y = cvtpk(a.z * LOG2E, a.w * LOG2E);
            cv.u.z = cvtpk(b.x * LOG2E, b.y * LOG2E);
            cv.u.w = cvtpk(b.z * LOG2E, b.w * LOG2E);
            const int g = sub * 2 + j;
            const unsigned off = (unsigned)(k * 256 + ((g * 16) ^ ((k & 7) << 4)));
            *(bf16x8*)((char*)w_s + off) = cv.v;
        }
    }
    float bias[4];
#pragma unroll
    for (int nt = 0; nt < 4; ++nt) bias[nt] = conv_b[nt * 16 + l15] * LOG2E;

    bar_lgkm();   // W staged (prologue global loads stay in flight)

    // ---- hoist W-frags to registers (read LDS once per block) ----
    bf16x8 wf[4][4];
#pragma unroll
    for (int nt = 0; nt < 4; ++nt)
#pragma unroll
        for (int ks = 0; ks < 4; ++ks) {
            const unsigned wb = (unsigned)((nt * 16 + l15) * 256
                + ((ks * 64 + lg * 16) ^ ((l15 & 7) << 4)));
            wf[nt][ks] = *(const bf16x8*)((char*)w_s + wb);
        }

    f32x4 acc2[4];                  // vlad acc: [mt over k], c-slice = 16w+l15
#pragma unroll
    for (int mt = 0; mt < 4; ++mt) acc2[mt] = (f32x4){0.f, 0.f, 0.f, 0.f};
    float asum[4] = {0.f, 0.f, 0.f, 0.f};
    bf16x8 oct[4];                  // x bf16 octets: GEMM2 B-frags (own c-slice)

    // ---- pre-loop: convert raw(0) -> oct(0), stage xc(0), prefetch raw(1) ----
    {
#pragma unroll
        for (int ks = 0; ks < 4; ++ks) {
            const float4 A = raw[ks * 2];
            const float4 B = raw[ks * 2 + 1];
            union { u32x4 u; bf16x8 v; } cv;
            cv.u.x = cvtpk(A.x, A.y); cv.u.y = cvtpk(A.z, A.w);
            cv.u.z = cvtpk(B.x, B.y); cv.u.w = cvtpk(B.z, B.w);
            oct[ks] = cv.v;
        }
        const int c = 16 * w + l15;
#pragma unroll
        for (int ks = 0; ks < 4; ++ks) {
            const int pl = ks * 32 + lg * 8;
            const unsigned off = (unsigned)((c >> 2) * 1024 + (pl >> 4) * 128
                                            + (c & 3) * 32 + (pl & 15) * 2);
            *(bf16x8*)((char*)xc_s + off) = oct[ks];
        }
#pragma unroll
        for (int ks = 0; ks < 4; ++ks) {
            const float* p = xr0 + pb0 + 128 + ks * 32 + lg * 8;
            raw[ks * 2 + 0] = *(const float4*)(p);
            raw[ks * 2 + 1] = *(const float4*)(p + 4);
        }
    }

#pragma unroll
    for (int s = 0; s < NSUB; ++s) {
        bar_lgkm();   // B1: xc(s) staged (done in prev iteration's shadow)

        // ---- GEMM1: logits^T for own p-tile (16p x 64k), batched tr ----
        u32x2 trr[4][2];
#pragma unroll
        for (int ks = 0; ks < 4; ++ks) {
            const unsigned ab = xc_base
                + (unsigned)((ks * 8 + lg * 2) * 1024 + l15 * 2 + w * 128);
            trr[ks][0] = tr16(ab);
            trr[ks][1] = tr16_o1024(ab);
        }
        asm volatile("s_waitcnt lgkmcnt(0)" ::: "memory");
        __builtin_amdgcn_sched_barrier(0);

        f32x4 acc1[4];
#pragma unroll
        for (int nt = 0; nt < 4; ++nt) acc1[nt] = (f32x4){0.f, 0.f, 0.f, 0.f};
#pragma unroll
        for (int ks = 0; ks < 4; ++ks) {
            union { u32x4 u; bf16x8 v; } a0;
            a0.u = (u32x4){trr[ks][0].x, trr[ks][0].y, trr[ks][1].x, trr[ks][1].y};
#pragma unroll
            for (int nt = 0; nt < 4; ++nt)
                acc1[nt] = mfma16(a0.v, wf[nt][ks], acc1[nt]);
        }

        // ---- softmax over k=64 (4 r-iters; DPP row reduce, exp2 domain) ----
#pragma unroll
        for (int r = 0; r < 4; ++r) {
            float v0 = acc1[0][r] + bias[0];
            float v1 = acc1[1][r] + bias[1];
            float v2 = acc1[2][r] + bias[2];
            float v3 = acc1[3][r] + bias[3];
            float m = fmaxf(fmaxf(v0, v1), fmaxf(v2, v3));
            m = rowmax16(m);
            v0 = exp2f(v0 - m); v1 = exp2f(v1 - m);
            v2 = exp2f(v2 - m); v3 = exp2f(v3 - m);
            float sm = (v0 + v1) + (v2 + v3);
            sm = rowsum16(sm);
            const float inv = __builtin_amdgcn_rcpf(sm);
            v0 *= inv; v1 *= inv; v2 *= inv; v3 *= inv;
            asum[0] += v0; asum[1] += v1; asum[2] += v2; asum[3] += v3;
            acc1[0][r] = v0; acc1[1][r] = v1; acc1[2][r] = v2; acc1[3][r] = v3;
        }

        // ---- write a -> a_s (swizzled); own p-tile ----
        {
            const int pbyte = w * 32 + lg * 8;
#pragma unroll
            for (int nt = 0; nt < 4; ++nt) {
                const int k = nt * 16 + l15;
                union { u32x2 u; bf16x4 v; } pk4;
                pk4.u.x = cvtpk(acc1[nt][0], acc1[nt][1]);
                pk4.u.y = cvtpk(acc1[nt][2], acc1[nt][3]);
                const unsigned off =
                    (unsigned)(k * 256 + (pbyte ^ ((k & 7) << 4)));
                *(bf16x4*)((char*)a_s + off) = pk4.v;
            }
        }
        bar_lgkm();   // B2: a(s) ready; all GEMM1(s) tr-reads drained

        // ---- GEMM2(s)  ||  convert+stage xc(s+1)  ||  prefetch raw(s+2) ----
        // GEMM2 uses oct(s) (registers) + a_s; staging writes xc only.
        bf16x8 noct[4];
        if (s + 1 < NSUB) {
#pragma unroll
            for (int ks = 0; ks < 4; ++ks) {
                const float4 A = raw[ks * 2];
                const float4 B = raw[ks * 2 + 1];
                union { u32x4 u; bf16x8 v; } cv;
                cv.u.x = cvtpk(A.x, A.y); cv.u.y = cvtpk(A.z, A.w);
                cv.u.z = cvtpk(B.x, B.y); cv.u.w = cvtpk(B.z, B.w);
                noct[ks] = cv.v;
            }
        }
#pragma unroll
        for (int ks = 0; ks < 4; ++ks) {
            bf16x8 af[4];
#pragma unroll
            for (int mt = 0; mt < 4; ++mt) {
                const int k = mt * 16 + l15;
                const unsigned off = (unsigned)(k * 256
                    + ((ks * 64 + lg * 16) ^ ((k & 7) << 4)));
                af[mt] = *(const bf16x8*)((char*)a_s + off);
            }
#pragma unroll
            for (int mt = 0; mt < 4; ++mt)
                acc2[mt] = mfma16(af[mt], oct[ks], acc2[mt]);
        }
        if (s + 1 < NSUB) {
            const int c = 16 * w + l15;
#pragma unroll
            for (int ks = 0; ks < 4; ++ks) {
                const int pl = ks * 32 + lg * 8;
                const unsigned off = (unsigned)((c >> 2) * 1024 + (pl >> 4) * 128
                                                + (c & 3) * 32 + (pl & 15) * 2);
                *(bf16x8*)((char*)xc_s + off) = noct[ks];
                oct[ks] = noct[ks];
            }
            if (s + 2 < NSUB) {
#pragma unroll
                for (int ks = 0; ks < 4; ++ks) {
                    const float* p = xr0 + pb0 + (s + 2) * 128 + ks * 32 + lg * 8;
                    raw[ks * 2 + 0] = *(const float4*)(p);
                    raw[ks * 2 + 1] = *(const float4*)(p + 4);
                }
            }
        }
    }

    // ---- write partials: part[bid][k][c], asum at c=128 ----
    const long pbase = (long)blockIdx.x * PART_BLK;
    {
        const int c = 16 * w + l15;
#pragma unroll
        for (int mt = 0; mt < 4; ++mt)
#pragma unroll
            for (int r = 0; r < 4; ++r) {
                const int k = mt * 16 + lg * 4 + r;
                part[pbase + (long)k * PART_ROW + c] = acc2[mt][r];
            }
    }
#pragma unroll
    for (int nt = 0; nt < 4; ++nt) {
        float a = asum[nt];
        a += __shfl_xor(a, 16);
        a += __shfl_xor(a, 32);
        if (lg == 0) asred[w * 64 + nt * 16 + l15] = a;
    }
    __syncthreads();
    if (t < 64) {
        float a = 0.f;
#pragma unroll
        for (int j = 0; j < 8; ++j) a += asred[j * 64 + t];
        part[pbase + (long)t * PART_ROW + 128] = a;
    }
}

// ---------------------------------------------------------------------------
// Kernel B (== R12): reduce partials, subtract asum*centers, intra-normalize.
// ---------------------------------------------------------------------------
__global__ __launch_bounds__(128)
void k_reduce_norm(const float* __restrict__ part, const float* __restrict__ centers,
                   unsigned short* __restrict__ vn16, float* __restrict__ rsq)
{
    const int b = blockIdx.x;
    const int n = b >> 6, k = b & 63;
    const int c = threadIdx.x;
    float acc = 0.f, as = 0.f;
#pragma unroll
    for (int ch = 0; ch < CHUNKS; ++ch) {
        const float* p = part + ((long)(n * CHUNKS + ch) * PART_BLK + k * PART_ROW);
        acc += p[c];
        as  += p[128];
    }
    const float v = fmaf(-as, centers[k * C_DIM + c], acc);
    float sq = v * v;
#pragma unroll
    for (int m = 1; m < 64; m <<= 1) sq += __shfl_xor(sq, m);
    __shared__ float red[2];
    if ((c & 63) == 0) red[c >> 6] = sq;
    __syncthreads();
    const float total = red[0] + red[1];
    const float s = 1.0f / fmaxf(sqrtf(total), 1e-12f);
    vn16[(long)n * 8192 + k * C_DIM + c] = bf1(v * s);
    if (c == 0) rsq[n * K_CL + k] = total * s * s;
}

// ---------------------------------------------------------------------------
// Kernel C (== R12): MLP GEMM, LDS-staged coalesced. grid = 256.
// ---------------------------------------------------------------------------
__global__ __launch_bounds__(256)
void k_mlp_mfma(const unsigned short* __restrict__ vn16,
                const float* __restrict__ mlp_w, float* __restrict__ part2)
{
    __shared__ short wt[8192];   // W  tile bf16 [32 o][256 j], swizzled, 16 KB
    __shared__ short vt[8192];   // vn tile bf16 [32 n][256 j], swizzled, 16 KB

    const int t  = threadIdx.x;
    const int og = blockIdx.x & 7;
    const int jc = blockIdx.x >> 3;
    const int j0 = jc * 256;

    {
        const int r = t >> 3, sub = t & 7;
        const float* wp = mlp_w + (long)(og * 32 + r) * 8192 + j0;
#pragma unroll
        for (int i = 0; i < 8; ++i) {
            const int jl = i * 32 + sub * 4;
            float4 a = *(const float4*)(wp + jl);
            union { u32x2 u; bf16x4 v; } cv;
            cv.u.x = cvtpk(a.x, a.y);
            cv.u.y = cvtpk(a.z, a.w);
            const unsigned off = (unsigned)(r * 512 + ((jl * 2) ^ ((r & 7) << 4)));
            *(bf16x4*)((char*)wt + off) = cv.v;
        }
    }
    {
        const int r = t >> 3, sub = t & 7;
        const unsigned short* vp = vn16 + (long)r * 8192 + j0;
#pragma unroll
        for (int i = 0; i < 4; ++i) {
            const int jl = i * 64 + sub * 8;
            bf16x8 v = *(const bf16x8*)(vp + jl);
            const unsigned off = (unsigned)(r * 512 + ((jl * 2) ^ ((r & 7) << 4)));
            *(bf16x8*)((char*)vt + off) = v;
        }
    }
    __syncthreads();

    const int w = t >> 6, l = t & 63, l15 = l & 15, lg = l >> 4;
    const int mt = w >> 1, ot = w & 1;
    f32x4 acc = (f32x4){0.f, 0.f, 0.f, 0.f};
#pragma unroll
    for (int kk = 0; kk < 8; ++kk) {
        const int rowa = mt * 16 + l15;
        const int rowb = ot * 16 + l15;
        const int jb = (kk * 32 + lg * 8) * 2;
        bf16x8 af = *(const bf16x8*)((char*)vt
                        + (unsigned)(rowa * 512 + (jb ^ ((rowa & 7) << 4))));
        bf16x8 bf = *(const bf16x8*)((char*)wt
                        + (unsigned)(rowb * 512 + (jb ^ ((rowb & 7) << 4))));
        acc = mfma16(af, bf, acc);
    }
#pragma unroll
    for (int r = 0; r < 4; ++r) {
        const int nn = mt * 16 + lg * 4 + r;
        const int oo = og * 32 + ot * 16 + l15;
        part2[(long)nn * 8192 + jc * 256 + oo] = acc[r];
    }
}

// ---------------------------------------------------------------------------
// Kernel D (== R12): reduce jc-slices, global-norm, bias, final L2 norm.
// ---------------------------------------------------------------------------
__global__ __launch_bounds__(1024)
void k_finalize(const float* __restrict__ part2, const float* __restrict__ mlp_b,
                const float* __restrict__ rsq, float* __restrict__ out)
{
    __shared__ float psum[4][256];
    __shared__ float red[4];
    const int n = blockIdx.x;
    const int t = threadIdx.x;
    const int o = t & 255, q = t >> 8;

    float acc = 0.f;
#pragma unroll
    for (int j = 0; j < 8; ++j)
        acc += part2[(long)n * 8192 + (q * 8 + j) * 256 + o];
    psum[q][o] = acc;
    __syncthreads();

    float y = 0.f;
    if (q == 0) {
        float g = 0.f;
#pragma unroll
        for (int i = 0; i < 16; ++i) {
            const float4 r = *(const float4*)&rsq[n * K_CL + i * 4];
            g += r.x + r.y + r.z + r.w;
        }
        const float s = 1.0f / fmaxf(sqrtf(g), 1e-12f);
        const float tot = psum[0][o] + psum[1][o] + psum[2][o] + psum[3][o];
        y = fmaf(tot * s, 1.0f, mlp_b[o]);
        float sq = y * y;
#pragma unroll
        for (int m = 1; m < 64; m <<= 1) sq += __shfl_xor(sq, m);
        if ((o & 63) == 0) red[o >> 6] = sq;
    }
    __syncthreads();
    if (q == 0) {
        const float tot2 = red[0] + red[1] + red[2] + red[3];
        out[n * OUT_D + o] = y / fmaxf(sqrtf(tot2), 1e-12f);
    }
}

// ---------------------------------------------------------------------------
extern "C" void kernel_launch(void* const* d_in, const int* in_sizes, int n_in,
                              void* d_out, int out_size, void* d_ws, size_t ws_size,
                              hipStream_t stream)
{
    const float* x       = (const float*)d_in[0];
    const float* centers = (const float*)d_in[1];
    const float* conv_w  = (const float*)d_in[2];
    const float* conv_b  = (const float*)d_in[3];
    const float* mlp_w   = (const float*)d_in[4];
    const float* mlp_b   = (const float*)d_in[5];

    float* ws = (float*)d_ws;
    float* part = ws;                                   // 256*8448 f
    unsigned short* vn16 = (unsigned short*)(part + 256 * PART_BLK);  // 262,144 u16
    float* rsq   = (float*)(vn16 + 32 * 8192);          // 2,048 f
    float* part2 = rsq + 2048;                          // 32*8192 f

    k_vlad_mfma<<<dim3(256), dim3(512), 0, stream>>>(x, conv_w, conv_b, part);
    k_reduce_norm<<<dim3(2048), dim3(128), 0, stream>>>(part, centers, vn16, rsq);
    k_mlp_mfma<<<dim3(256), dim3(256), 0, stream>>>(vn16, mlp_w, part2);
    k_finalize<<<dim3(32), dim3(1024), 0, stream>>>(part2, mlp_b, rsq, (float*)d_out);
}